// Round 1
// baseline (374.960 us; speedup 1.0000x reference)
//
#include <hip/hip_runtime.h>

#define MDIM 64
#define NDIM 256
#define LUT_N 2048

// ---------------------------------------------------------------------------
// Kernel 1: build LUT of tp_w(r) = (MLP(rbf(r)) ) * env(r), 2048 x 256.
// One 64-thread block per LUT point.
// ---------------------------------------------------------------------------
__global__ __launch_bounds__(64) void lut_kernel(
    const float* __restrict__ w1, const float* __restrict__ b1,
    const float* __restrict__ w2, const float* __restrict__ b2,
    const float* __restrict__ w3, const float* __restrict__ b3,
    float* __restrict__ lut)
{
    __shared__ float h1[64];
    __shared__ float h2[64];
    int p = blockIdx.x;
    int j = threadIdx.x;
    float r = 0.5f + (4.5f / (float)(LUT_N - 1)) * (float)p;

    float acc = b1[j];
    const float cnorm = 0.6324555320336759f;  // sqrt(2/5)
    #pragma unroll
    for (int k = 0; k < 8; ++k) {
        float freq = (float)(k + 1) * (3.14159265358979323846f / 5.0f);
        float rb = cnorm * sinf(freq * r) / r;
        acc = fmaf(rb, w1[k * 64 + j], acc);
    }
    float h = acc / (1.0f + expf(-acc));  // silu
    h1[j] = h;
    __syncthreads();

    acc = b2[j];
    #pragma unroll 8
    for (int m = 0; m < 64; ++m) acc = fmaf(h1[m], w2[m * 64 + j], acc);
    h = acc / (1.0f + expf(-acc));
    h2[j] = h;
    __syncthreads();

    float u = r * 0.2f;
    float u2 = u * u, u4 = u2 * u2, u5 = u4 * u, u6 = u5 * u, u7 = u6 * u;
    float env = (u < 1.0f) ? (1.0f - 21.0f * u5 + 35.0f * u6 - 15.0f * u7) : 0.0f;

    #pragma unroll
    for (int q = 0; q < 4; ++q) {
        float o = b3[q * 64 + j];
        #pragma unroll 8
        for (int m = 0; m < 64; ++m) o = fmaf(h2[m], w3[m * 256 + q * 64 + j], o);
        lut[(size_t)p * NDIM + q * 64 + j] = o * env;
    }
}

// ---------------------------------------------------------------------------
// CSR build: histogram of col, exclusive scan, scatter edge ids.
// ---------------------------------------------------------------------------
__global__ void hist_kernel(const int* __restrict__ col, int E, int* __restrict__ counts)
{
    int i = blockIdx.x * 256 + threadIdx.x;
    if (i < E) atomicAdd(&counts[col[i]], 1);
}

__global__ __launch_bounds__(1024) void scan_kernel(
    const int* __restrict__ counts, int* __restrict__ row_ptr,
    int* __restrict__ cursor, int N)
{
    __shared__ int partial[1024];
    int t = threadIdx.x;
    int ch = (N + 1023) >> 10;
    int base = t * ch;
    int sum = 0;
    for (int i = 0; i < ch; ++i) {
        int idx = base + i;
        if (idx < N) sum += counts[idx];
    }
    partial[t] = sum;
    __syncthreads();
    for (int o = 1; o < 1024; o <<= 1) {
        int add = (t >= o) ? partial[t - o] : 0;
        __syncthreads();
        partial[t] += add;
        __syncthreads();
    }
    int run = partial[t] - sum;  // exclusive prefix for this chunk
    for (int i = 0; i < ch; ++i) {
        int idx = base + i;
        if (idx < N) {
            row_ptr[idx] = run;
            cursor[idx] = run;
            run += counts[idx];
        }
    }
    if (t == 1023) row_ptr[N] = partial[1023];
}

__global__ void scatter_kernel(const int* __restrict__ col, int E,
                               int* __restrict__ cursor, int* __restrict__ edge_list)
{
    int i = blockIdx.x * 256 + threadIdx.x;
    if (i < E) {
        int p = atomicAdd(&cursor[col[i]], 1);
        edge_list[p] = i;
    }
}

// ---------------------------------------------------------------------------
// Kernel 2 (heavy): one wave per destination node. Lane m owns channel m.
// Accumulate messages over incoming edges in registers, then fused
// linear (lin_w0 / lin_w1), layernorm, RMS-norm, residual add.
// ---------------------------------------------------------------------------
__global__ __launch_bounds__(256) void node_kernel(
    const float* __restrict__ nf,
    const int* __restrict__ eidx,       // [2, E]
    const float* __restrict__ evec,     // [E, 3]
    const float* __restrict__ elen,     // [E]
    const float* __restrict__ lut,      // [LUT_N, 256]
    const int* __restrict__ row_ptr,
    const int* __restrict__ edge_list,
    const float* __restrict__ lw0,      // [64, 64]
    const float* __restrict__ lw1,      // [64, 64]
    const float* __restrict__ g0,
    const float* __restrict__ be0,
    const float* __restrict__ g1,
    float* __restrict__ out,
    int N, int E)
{
    __shared__ float s_agg[4][NDIM];
    int tid = threadIdx.x;
    int wave = tid >> 6;
    int lane = tid & 63;
    int n = blockIdx.x * 4 + wave;
    bool active = (n < N);

    int start = active ? row_ptr[n] : 0;
    int end   = active ? row_ptr[n + 1] : 0;

    float acc0 = 0.0f, accx = 0.0f, accy = 0.0f, accz = 0.0f;

    for (int j = start; j < end; ++j) {
        int e = edge_list[j];
        e = __builtin_amdgcn_readfirstlane(e);
        int rsrc = eidx[e];
        rsrc = __builtin_amdgcn_readfirstlane(rsrc);
        float vx = evec[3 * e + 0];
        float vy = evec[3 * e + 1];
        float vz = evec[3 * e + 2];
        float len = elen[e];

        float inv = rsqrtf(vx * vx + vy * vy + vz * vz);
        const float SQ3 = 1.7320508075688772f;
        float shx = SQ3 * inv * vx;
        float shy = SQ3 * inv * vy;
        float shz = SQ3 * inv * vz;

        // LUT interpolation of tp_w
        float x = (len - 0.5f) * ((float)(LUT_N - 1) / 4.5f);
        x = fminf(fmaxf(x, 0.0f), (float)(LUT_N - 1));
        int i0 = (int)x;
        i0 = min(i0, LUT_N - 2);
        float f = x - (float)i0;
        const float* L0 = lut + (size_t)i0 * NDIM;
        const float* L1 = L0 + NDIM;
        float wa = fmaf(f, L1[lane]       - L0[lane],       L0[lane]);
        float wb = fmaf(f, L1[64 + lane]  - L0[64 + lane],  L0[64 + lane]);
        float wc = fmaf(f, L1[128 + lane] - L0[128 + lane], L0[128 + lane]);
        float wd = fmaf(f, L1[192 + lane] - L0[192 + lane], L0[192 + lane]);

        const float* nr = nf + (size_t)rsrc * NDIM;
        float s0  = nr[lane];
        float s1x = nr[64 + 3 * lane + 0];
        float s1y = nr[64 + 3 * lane + 1];
        float s1z = nr[64 + 3 * lane + 2];

        float dot = s1x * shx + s1y * shy + s1z * shz;
        acc0 += wa * s0 + wd * dot;
        float wcs0 = wc * s0;
        accx += wb * s1x + wcs0 * shx;
        accy += wb * s1y + wcs0 * shy;
        accz += wb * s1z + wcs0 * shz;
    }

    const float INVS2 = 0.7071067811865476f;
    s_agg[wave][lane]              = acc0 * INVS2;
    s_agg[wave][64 + 3 * lane + 0] = accx * INVS2;
    s_agg[wave][64 + 3 * lane + 1] = accy * INVS2;
    s_agg[wave][64 + 3 * lane + 2] = accz * INVS2;
    __syncthreads();

    // transform: a0 = agg0 @ lin_w0 / 8 ; a1[k,i] = sum_m agg1[m,i]*lin_w1[m,k] / 8
    const float* ag = s_agg[wave];
    float a0 = 0.0f, t1x = 0.0f, t1y = 0.0f, t1z = 0.0f;
    #pragma unroll 8
    for (int m = 0; m < 64; ++m) {
        float w0v = lw0[m * 64 + lane];
        float w1v = lw1[m * 64 + lane];
        float gg0 = ag[m];
        a0 = fmaf(gg0, w0v, a0);
        float gx = ag[64 + 3 * m + 0];
        float gy = ag[64 + 3 * m + 1];
        float gz = ag[64 + 3 * m + 2];
        t1x = fmaf(gx, w1v, t1x);
        t1y = fmaf(gy, w1v, t1y);
        t1z = fmaf(gz, w1v, t1z);
    }
    const float sc = 0.125f;  // 1/sqrt(64)
    a0 *= sc; t1x *= sc; t1y *= sc; t1z *= sc;

    // layernorm over a0 across 64 lanes
    float mu = a0;
    #pragma unroll
    for (int o = 32; o > 0; o >>= 1) mu += __shfl_xor(mu, o);
    mu *= (1.0f / 64.0f);
    float d = a0 - mu;
    float var = d * d;
    #pragma unroll
    for (int o = 32; o > 0; o >>= 1) var += __shfl_xor(var, o);
    var *= (1.0f / 64.0f);
    float o0 = g0[lane] * d * rsqrtf(var + 1e-5f) + be0[lane];

    // RMS over vnorm2 across 64 lanes
    float vn = t1x * t1x + t1y * t1y + t1z * t1z;
    float ms = vn;
    #pragma unroll
    for (int o = 32; o > 0; o >>= 1) ms += __shfl_xor(ms, o);
    ms *= (1.0f / 64.0f);
    float rinv = rsqrtf(ms + 1e-5f);
    float gg = g1[lane];

    if (active) {
        size_t b = (size_t)n * NDIM;
        out[b + lane]              = nf[b + lane] + o0;
        out[b + 64 + 3 * lane + 0] = nf[b + 64 + 3 * lane + 0] + gg * t1x * rinv;
        out[b + 64 + 3 * lane + 1] = nf[b + 64 + 3 * lane + 1] + gg * t1y * rinv;
        out[b + 64 + 3 * lane + 2] = nf[b + 64 + 3 * lane + 2] + gg * t1z * rinv;
    }
}

// ---------------------------------------------------------------------------
extern "C" void kernel_launch(void* const* d_in, const int* in_sizes, int n_in,
                              void* d_out, int out_size, void* d_ws, size_t ws_size,
                              hipStream_t stream)
{
    const float* nf   = (const float*)d_in[0];
    const int*   eidx = (const int*)d_in[1];
    const float* evec = (const float*)d_in[2];
    const float* elen = (const float*)d_in[3];
    const float* w1   = (const float*)d_in[4];
    const float* b1   = (const float*)d_in[5];
    const float* w2   = (const float*)d_in[6];
    const float* b2   = (const float*)d_in[7];
    const float* w3   = (const float*)d_in[8];
    const float* b3   = (const float*)d_in[9];
    const float* lw0  = (const float*)d_in[10];
    const float* lw1  = (const float*)d_in[11];
    const float* g0   = (const float*)d_in[12];
    const float* be0  = (const float*)d_in[13];
    const float* g1   = (const float*)d_in[14];

    int N = in_sizes[0] / NDIM;
    int E = in_sizes[3];

    char* ws = (char*)d_ws;
    size_t off = 0;
    float* lut = (float*)(ws + off);       off += (size_t)LUT_N * NDIM * 4;
    int* counts = (int*)(ws + off);        off += (size_t)N * 4;       off = (off + 255) & ~(size_t)255;
    int* row_ptr = (int*)(ws + off);       off += (size_t)(N + 1) * 4; off = (off + 255) & ~(size_t)255;
    int* cursor = (int*)(ws + off);        off += (size_t)N * 4;       off = (off + 255) & ~(size_t)255;
    int* edge_list = (int*)(ws + off);     off += (size_t)E * 4;

    const int* col = eidx + E;

    hipMemsetAsync(counts, 0, (size_t)N * 4, stream);
    lut_kernel<<<LUT_N, 64, 0, stream>>>(w1, b1, w2, b2, w3, b3, lut);
    hist_kernel<<<(E + 255) / 256, 256, 0, stream>>>(col, E, counts);
    scan_kernel<<<1, 1024, 0, stream>>>(counts, row_ptr, cursor, N);
    scatter_kernel<<<(E + 255) / 256, 256, 0, stream>>>(col, E, cursor, edge_list);
    node_kernel<<<(N + 3) / 4, 256, 0, stream>>>(nf, eidx, evec, elen, lut,
                                                 row_ptr, edge_list, lw0, lw1,
                                                 g0, be0, g1, (float*)d_out, N, E);
}

// Round 2
// 370.698 us; speedup vs baseline: 1.0115x; 1.0115x over previous
//
#include <hip/hip_runtime.h>

#define NDIM 256
#define LUT_N 2048

// ---------------------------------------------------------------------------
// Kernel 1a: LUT values tp_w(r) = MLP(rbf(r)) * env(r), LUT_N x 256.
// ---------------------------------------------------------------------------
__global__ __launch_bounds__(64) void lut_kernel(
    const float* __restrict__ w1, const float* __restrict__ b1,
    const float* __restrict__ w2, const float* __restrict__ b2,
    const float* __restrict__ w3, const float* __restrict__ b3,
    float* __restrict__ lutv)
{
    __shared__ float h1[64];
    __shared__ float h2[64];
    int p = blockIdx.x;
    int j = threadIdx.x;
    float r = 0.5f + (4.5f / (float)(LUT_N - 1)) * (float)p;

    float acc = b1[j];
    const float cnorm = 0.6324555320336759f;  // sqrt(2/5)
    #pragma unroll
    for (int k = 0; k < 8; ++k) {
        float freq = (float)(k + 1) * (3.14159265358979323846f / 5.0f);
        float rb = cnorm * sinf(freq * r) / r;
        acc = fmaf(rb, w1[k * 64 + j], acc);
    }
    float h = acc / (1.0f + expf(-acc));  // silu
    h1[j] = h;
    __syncthreads();

    acc = b2[j];
    #pragma unroll 8
    for (int m = 0; m < 64; ++m) acc = fmaf(h1[m], w2[m * 64 + j], acc);
    h = acc / (1.0f + expf(-acc));
    h2[j] = h;
    __syncthreads();

    float u = r * 0.2f;
    float u2 = u * u, u4 = u2 * u2, u5 = u4 * u, u6 = u5 * u, u7 = u6 * u;
    float env = (u < 1.0f) ? (1.0f - 21.0f * u5 + 35.0f * u6 - 15.0f * u7) : 0.0f;

    #pragma unroll
    for (int q = 0; q < 4; ++q) {
        float o = b3[q * 64 + j];
        #pragma unroll 8
        for (int m = 0; m < 64; ++m) o = fmaf(h2[m], w3[m * 256 + q * 64 + j], o);
        lutv[(size_t)p * NDIM + q * 64 + j] = o * env;
    }
}

// Kernel 1b: pack LUT into (value, delta-to-next) float2 pairs.
__global__ void pair_kernel(const float* __restrict__ v, float2* __restrict__ lut2, int total)
{
    int i = blockIdx.x * 256 + threadIdx.x;
    if (i < total) {
        float a = v[i];
        float b = (i < total - NDIM) ? v[i + NDIM] : a;
        lut2[i] = make_float2(a, b - a);
    }
}

// ---------------------------------------------------------------------------
// CSR build: histogram of col, single-block scan, payload scatter.
// ---------------------------------------------------------------------------
__global__ void hist_kernel(const int* __restrict__ col, int E, int* __restrict__ counts)
{
    int i = blockIdx.x * 256 + threadIdx.x;
    if (i < E) atomicAdd(&counts[col[i]], 1);
}

__global__ __launch_bounds__(1024) void scan_kernel(
    const int* __restrict__ counts, int* __restrict__ row_ptr,
    int* __restrict__ cursor, int N)
{
    __shared__ int partial[1024];
    int t = threadIdx.x;
    int ch = (N + 1023) >> 10;
    int base = t * ch;
    int sum = 0;
    for (int i = 0; i < ch; ++i) {
        int idx = base + i;
        if (idx < N) sum += counts[idx];
    }
    partial[t] = sum;
    __syncthreads();
    for (int o = 1; o < 1024; o <<= 1) {
        int add = (t >= o) ? partial[t - o] : 0;
        __syncthreads();
        partial[t] += add;
        __syncthreads();
    }
    int run = partial[t] - sum;
    for (int i = 0; i < ch; ++i) {
        int idx = base + i;
        if (idx < N) {
            row_ptr[idx] = run;
            cursor[idx] = run;
            run += counts[idx];
        }
    }
    if (t == 1023) row_ptr[N] = partial[1023];
}

// Scatter edge payload into CSR order: source id + {sh1, lut coordinate}.
__global__ void scatter_kernel(const int* __restrict__ row, const int* __restrict__ col,
                               const float* __restrict__ evec, const float* __restrict__ elen,
                               int E, int* __restrict__ cursor,
                               int* __restrict__ er, float4* __restrict__ em)
{
    int i = blockIdx.x * 256 + threadIdx.x;
    if (i < E) {
        int p = atomicAdd(&cursor[col[i]], 1);
        float vx = evec[3 * i + 0], vy = evec[3 * i + 1], vz = evec[3 * i + 2];
        float inv = rsqrtf(vx * vx + vy * vy + vz * vz) * 1.7320508075688772f; // sqrt(3)/|v|
        float x = (elen[i] - 0.5f) * ((float)(LUT_N - 1) / 4.5f);
        x = fminf(fmaxf(x, 0.0f), (float)(LUT_N - 1));
        er[p] = row[i];
        em[p] = make_float4(vx * inv, vy * inv, vz * inv, x);
    }
}

// ---------------------------------------------------------------------------
// Kernel 2 (heavy): one wave per destination node, lane = channel.
// Metadata batch-loaded (one edge per lane) + shfl broadcast; gathers
// software-pipelined 4-deep.
// ---------------------------------------------------------------------------
struct EV {
    float f;
    float2 pa, pb, pc, pd;
    float s0;
    float3 s1;
    float shx, shy, shz;
};

__device__ __forceinline__ EV grab_edge(int k, int m_rsrc, float m_shx, float m_shy,
                                        float m_shz, float m_x, int lane,
                                        const float2* __restrict__ lut2,
                                        const float* __restrict__ nf)
{
    EV e;
    int rsrc = __shfl(m_rsrc, k);
    e.shx = __shfl(m_shx, k);
    e.shy = __shfl(m_shy, k);
    e.shz = __shfl(m_shz, k);
    float x = __shfl(m_x, k);
    int i0 = (int)x;
    i0 = min(i0, LUT_N - 2);
    e.f = x - (float)i0;
    const float2* L = lut2 + (size_t)i0 * NDIM + lane;
    e.pa = L[0];
    e.pb = L[64];
    e.pc = L[128];
    e.pd = L[192];
    const float* nr = nf + (size_t)rsrc * NDIM;
    e.s0 = nr[lane];
    e.s1 = ((const float3*)(nr + 64))[lane];
    return e;
}

__device__ __forceinline__ void accum_edge(const EV& e, float& acc0, float& accx,
                                           float& accy, float& accz)
{
    float wa = fmaf(e.f, e.pa.y, e.pa.x);
    float wb = fmaf(e.f, e.pb.y, e.pb.x);
    float wc = fmaf(e.f, e.pc.y, e.pc.x);
    float wd = fmaf(e.f, e.pd.y, e.pd.x);
    float dot = e.s1.x * e.shx + e.s1.y * e.shy + e.s1.z * e.shz;
    acc0 += wa * e.s0 + wd * dot;
    float wcs0 = wc * e.s0;
    accx = fmaf(wb, e.s1.x, fmaf(wcs0, e.shx, accx));
    accy = fmaf(wb, e.s1.y, fmaf(wcs0, e.shy, accy));
    accz = fmaf(wb, e.s1.z, fmaf(wcs0, e.shz, accz));
}

__global__ __launch_bounds__(256) void node_kernel(
    const float* __restrict__ nf,
    const float2* __restrict__ lut2,
    const int* __restrict__ row_ptr,
    const int* __restrict__ er,
    const float4* __restrict__ em,
    const float* __restrict__ lw0,
    const float* __restrict__ lw1,
    const float* __restrict__ g0,
    const float* __restrict__ be0,
    const float* __restrict__ g1,
    float* __restrict__ out,
    int N)
{
    __shared__ float s_agg[4][NDIM];
    int tid = threadIdx.x;
    int wave = tid >> 6;
    int lane = tid & 63;
    int n = blockIdx.x * 4 + wave;
    bool active = (n < N);

    int start = active ? row_ptr[n] : 0;
    int end   = active ? row_ptr[n + 1] : 0;

    float acc0 = 0.0f, accx = 0.0f, accy = 0.0f, accz = 0.0f;

    for (int j0 = start; j0 < end; j0 += 64) {
        int nk = end - j0;
        if (nk > 64) nk = 64;
        int idx = j0 + lane;
        if (idx >= end) idx = end - 1;
        int m_rsrc = er[idx];
        float4 mm = em[idx];

        int k = 0;
        for (; k + 4 <= nk; k += 4) {
            EV e0 = grab_edge(k + 0, m_rsrc, mm.x, mm.y, mm.z, mm.w, lane, lut2, nf);
            EV e1 = grab_edge(k + 1, m_rsrc, mm.x, mm.y, mm.z, mm.w, lane, lut2, nf);
            EV e2 = grab_edge(k + 2, m_rsrc, mm.x, mm.y, mm.z, mm.w, lane, lut2, nf);
            EV e3 = grab_edge(k + 3, m_rsrc, mm.x, mm.y, mm.z, mm.w, lane, lut2, nf);
            accum_edge(e0, acc0, accx, accy, accz);
            accum_edge(e1, acc0, accx, accy, accz);
            accum_edge(e2, acc0, accx, accy, accz);
            accum_edge(e3, acc0, accx, accy, accz);
        }
        for (; k < nk; ++k) {
            EV e = grab_edge(k, m_rsrc, mm.x, mm.y, mm.z, mm.w, lane, lut2, nf);
            accum_edge(e, acc0, accx, accy, accz);
        }
    }

    const float INVS2 = 0.7071067811865476f;
    s_agg[wave][lane]              = acc0 * INVS2;
    s_agg[wave][64 + 3 * lane + 0] = accx * INVS2;
    s_agg[wave][64 + 3 * lane + 1] = accy * INVS2;
    s_agg[wave][64 + 3 * lane + 2] = accz * INVS2;
    __syncthreads();

    const float* ag = s_agg[wave];
    float a0 = 0.0f, t1x = 0.0f, t1y = 0.0f, t1z = 0.0f;
    #pragma unroll 8
    for (int m = 0; m < 64; ++m) {
        float w0v = lw0[m * 64 + lane];
        float w1v = lw1[m * 64 + lane];
        float gg0 = ag[m];
        a0 = fmaf(gg0, w0v, a0);
        float gx = ag[64 + 3 * m + 0];
        float gy = ag[64 + 3 * m + 1];
        float gz = ag[64 + 3 * m + 2];
        t1x = fmaf(gx, w1v, t1x);
        t1y = fmaf(gy, w1v, t1y);
        t1z = fmaf(gz, w1v, t1z);
    }
    const float sc = 0.125f;  // 1/sqrt(64)
    a0 *= sc; t1x *= sc; t1y *= sc; t1z *= sc;

    // layernorm over a0 across 64 lanes
    float mu = a0;
    #pragma unroll
    for (int o = 32; o > 0; o >>= 1) mu += __shfl_xor(mu, o);
    mu *= (1.0f / 64.0f);
    float d = a0 - mu;
    float var = d * d;
    #pragma unroll
    for (int o = 32; o > 0; o >>= 1) var += __shfl_xor(var, o);
    var *= (1.0f / 64.0f);
    float o0 = g0[lane] * d * rsqrtf(var + 1e-5f) + be0[lane];

    // RMS over vnorm2 across 64 lanes
    float vn = t1x * t1x + t1y * t1y + t1z * t1z;
    float ms = vn;
    #pragma unroll
    for (int o = 32; o > 0; o >>= 1) ms += __shfl_xor(ms, o);
    ms *= (1.0f / 64.0f);
    float rinv = rsqrtf(ms + 1e-5f);
    float gg = g1[lane];

    if (active) {
        size_t b = (size_t)n * NDIM;
        out[b + lane] = nf[b + lane] + o0;
        float3 rv = ((const float3*)(nf + b + 64))[lane];
        float3 ov;
        ov.x = rv.x + gg * t1x * rinv;
        ov.y = rv.y + gg * t1y * rinv;
        ov.z = rv.z + gg * t1z * rinv;
        ((float3*)(out + b + 64))[lane] = ov;
    }
}

// ---------------------------------------------------------------------------
extern "C" void kernel_launch(void* const* d_in, const int* in_sizes, int n_in,
                              void* d_out, int out_size, void* d_ws, size_t ws_size,
                              hipStream_t stream)
{
    const float* nf   = (const float*)d_in[0];
    const int*   eidx = (const int*)d_in[1];
    const float* evec = (const float*)d_in[2];
    const float* elen = (const float*)d_in[3];
    const float* w1   = (const float*)d_in[4];
    const float* b1   = (const float*)d_in[5];
    const float* w2   = (const float*)d_in[6];
    const float* b2   = (const float*)d_in[7];
    const float* w3   = (const float*)d_in[8];
    const float* b3   = (const float*)d_in[9];
    const float* lw0  = (const float*)d_in[10];
    const float* lw1  = (const float*)d_in[11];
    const float* g0   = (const float*)d_in[12];
    const float* be0  = (const float*)d_in[13];
    const float* g1   = (const float*)d_in[14];

    int N = in_sizes[0] / NDIM;
    int E = in_sizes[3];

    char* ws = (char*)d_ws;
    size_t off = 0;
    auto align256 = [&]() { off = (off + 255) & ~(size_t)255; };
    float* lutv = (float*)(ws + off);   off += (size_t)LUT_N * NDIM * 4;  align256();
    float2* lut2 = (float2*)(ws + off); off += (size_t)LUT_N * NDIM * 8;  align256();
    int* counts = (int*)(ws + off);     off += (size_t)N * 4;             align256();
    int* row_ptr = (int*)(ws + off);    off += (size_t)(N + 1) * 4;       align256();
    int* cursor = (int*)(ws + off);     off += (size_t)N * 4;             align256();
    int* er = (int*)(ws + off);         off += (size_t)E * 4;             align256();
    float4* em = (float4*)(ws + off);   off += (size_t)E * 16;

    const int* row = eidx;
    const int* col = eidx + E;

    hipMemsetAsync(counts, 0, (size_t)N * 4, stream);
    lut_kernel<<<LUT_N, 64, 0, stream>>>(w1, b1, w2, b2, w3, b3, lutv);
    pair_kernel<<<(LUT_N * NDIM + 255) / 256, 256, 0, stream>>>(lutv, lut2, LUT_N * NDIM);
    hist_kernel<<<(E + 255) / 256, 256, 0, stream>>>(col, E, counts);
    scan_kernel<<<1, 1024, 0, stream>>>(counts, row_ptr, cursor, N);
    scatter_kernel<<<(E + 255) / 256, 256, 0, stream>>>(row, col, evec, elen, E, cursor, er, em);
    node_kernel<<<(N + 3) / 4, 256, 0, stream>>>(nf, lut2, row_ptr, er, em,
                                                 lw0, lw1, g0, be0, g1,
                                                 (float*)d_out, N);
}

// Round 3
// 317.340 us; speedup vs baseline: 1.1816x; 1.1681x over previous
//
#include <hip/hip_runtime.h>
#include <hip/hip_fp16.h>

#define NDIM 256
#define LUT_N 2048

// ---------------------------------------------------------------------------
// Kernel 1a: LUT values tp_w(r) = MLP(rbf(r)) * env(r), LUT_N x 256 floats.
// ---------------------------------------------------------------------------
__global__ __launch_bounds__(64) void lut_kernel(
    const float* __restrict__ w1, const float* __restrict__ b1,
    const float* __restrict__ w2, const float* __restrict__ b2,
    const float* __restrict__ w3, const float* __restrict__ b3,
    float* __restrict__ lutv)
{
    __shared__ float h1[64];
    __shared__ float h2[64];
    int p = blockIdx.x;
    int j = threadIdx.x;
    float r = 0.5f + (4.5f / (float)(LUT_N - 1)) * (float)p;

    float acc = b1[j];
    const float cnorm = 0.6324555320336759f;  // sqrt(2/5)
    #pragma unroll
    for (int k = 0; k < 8; ++k) {
        float freq = (float)(k + 1) * (3.14159265358979323846f / 5.0f);
        float rb = cnorm * sinf(freq * r) / r;
        acc = fmaf(rb, w1[k * 64 + j], acc);
    }
    float h = acc / (1.0f + expf(-acc));  // silu
    h1[j] = h;
    __syncthreads();

    acc = b2[j];
    #pragma unroll 8
    for (int m = 0; m < 64; ++m) acc = fmaf(h1[m], w2[m * 64 + j], acc);
    h = acc / (1.0f + expf(-acc));
    h2[j] = h;
    __syncthreads();

    float u = r * 0.2f;
    float u2 = u * u, u4 = u2 * u2, u5 = u4 * u, u6 = u5 * u, u7 = u6 * u;
    float env = (u < 1.0f) ? (1.0f - 21.0f * u5 + 35.0f * u6 - 15.0f * u7) : 0.0f;

    #pragma unroll
    for (int q = 0; q < 4; ++q) {
        float o = b3[q * 64 + j];
        #pragma unroll 8
        for (int m = 0; m < 64; ++m) o = fmaf(h2[m], w3[m * 256 + q * 64 + j], o);
        lutv[(size_t)p * NDIM + q * 64 + j] = o * env;
    }
}

// ---------------------------------------------------------------------------
// Kernel 1b: pack LUT to fp16 (value, delta) pairs, layout [i][ch] = uint4:
//   half2{va,da}, half2{vb,db}, half2{vc,dc}, half2{vd,dd}
// ---------------------------------------------------------------------------
__global__ void pack_kernel(const float* __restrict__ v, uint4* __restrict__ lutp, int nrow)
{
    int t = blockIdx.x * 256 + threadIdx.x;
    if (t >= nrow * 64) return;
    int i = t >> 6;
    int ch = t & 63;
    int in = (i < nrow - 1) ? i + 1 : i;
    uint4 o;
    unsigned* ow = &o.x;
    #pragma unroll
    for (int q = 0; q < 4; ++q) {
        float a = v[(size_t)i * NDIM + q * 64 + ch];
        float b = v[(size_t)in * NDIM + q * 64 + ch];
        __half2 h2 = __floats2half2_rn(a, b - a);
        ow[q] = *reinterpret_cast<unsigned*>(&h2);
    }
    lutp[t] = o;
}

// ---------------------------------------------------------------------------
// CSR build: histogram of col, single-block scan, payload scatter.
// ---------------------------------------------------------------------------
__global__ void hist_kernel(const int* __restrict__ col, int E, int* __restrict__ counts)
{
    int i = blockIdx.x * 512 + threadIdx.x;
    if (i < E) atomicAdd(&counts[col[i]], 1);
}

__global__ __launch_bounds__(1024) void scan_kernel(
    const int* __restrict__ counts, int* __restrict__ row_ptr,
    int* __restrict__ cursor, int N)
{
    __shared__ int partial[1024];
    int t = threadIdx.x;
    int ch = (N + 1023) >> 10;
    int base = t * ch;
    int sum = 0;
    for (int i = 0; i < ch; ++i) {
        int idx = base + i;
        if (idx < N) sum += counts[idx];
    }
    partial[t] = sum;
    __syncthreads();
    for (int o = 1; o < 1024; o <<= 1) {
        int add = (t >= o) ? partial[t - o] : 0;
        __syncthreads();
        partial[t] += add;
        __syncthreads();
    }
    int run = partial[t] - sum;
    for (int i = 0; i < ch; ++i) {
        int idx = base + i;
        if (idx < N) {
            row_ptr[idx] = run;
            cursor[idx] = run;
            run += counts[idx];
        }
    }
    if (t == 1023) row_ptr[N] = partial[1023];
}

// Scatter payload in CSR order: em = {shx, shy, shz, bits(rsrc | i0<<16 | fq<<27)}.
// Requires N <= 65536 (here N = 40000).
__global__ void scatter_kernel(const int* __restrict__ row, const int* __restrict__ col,
                               const float* __restrict__ evec, const float* __restrict__ elen,
                               int E, int* __restrict__ cursor, float4* __restrict__ em)
{
    int i = blockIdx.x * 512 + threadIdx.x;
    if (i < E) {
        int p = atomicAdd(&cursor[col[i]], 1);
        float vx = evec[3 * i + 0], vy = evec[3 * i + 1], vz = evec[3 * i + 2];
        float inv = rsqrtf(vx * vx + vy * vy + vz * vz) * 1.7320508075688772f; // sqrt(3)/|v|
        float x = (elen[i] - 0.5f) * ((float)(LUT_N - 1) / 4.5f);
        x = fminf(fmaxf(x, 0.0f), (float)(LUT_N - 1) - 1.0e-3f);
        int i0 = (int)x;
        if (i0 > LUT_N - 2) i0 = LUT_N - 2;
        float fr = x - (float)i0;
        int fq = (int)(fr * 32.0f);
        fq = fq < 0 ? 0 : (fq > 31 ? 31 : fq);
        unsigned packed = (unsigned)row[i] | ((unsigned)i0 << 16) | ((unsigned)fq << 27);
        em[p] = make_float4(vx * inv, vy * inv, vz * inv, __uint_as_float(packed));
    }
}

// ---------------------------------------------------------------------------
// Kernel 2 (heavy): one wave per destination node, lane = channel.
// One shfl gates addresses; 3 vector loads per edge; unroll-4 pipeline.
// ---------------------------------------------------------------------------
struct EV {
    uint4 L;      // 4x half2 (value,delta) for wa,wb,wc,wd
    float s0;
    float3 s1;
    unsigned packed;
};

__device__ __forceinline__ EV grab_edge(int k, unsigned m_packed, int lane,
                                        const uint4* __restrict__ lutp,
                                        const float* __restrict__ nf)
{
    EV e;
    e.packed = (unsigned)__shfl((int)m_packed, k);
    int rsrc = (int)(e.packed & 0xFFFFu);
    int i0 = (int)((e.packed >> 16) & 0x7FFu);
    e.L = lutp[i0 * 64 + lane];
    const float* nr = nf + (size_t)rsrc * NDIM;
    e.s0 = nr[lane];
    e.s1 = ((const float3*)(nr + 64))[lane];
    return e;
}

__device__ __forceinline__ void accum_edge(const EV& e, int k,
                                           float m_shx, float m_shy, float m_shz,
                                           float& acc0, float& accx, float& accy, float& accz)
{
    float shx = __shfl(m_shx, k);
    float shy = __shfl(m_shy, k);
    float shz = __shfl(m_shz, k);
    float f = (float)((e.packed >> 27) & 31u) * (1.0f / 32.0f) + (1.0f / 64.0f);

    const __half2* hw = reinterpret_cast<const __half2*>(&e.L);
    float wa = fmaf(f, __high2float(hw[0]), __low2float(hw[0]));
    float wb = fmaf(f, __high2float(hw[1]), __low2float(hw[1]));
    float wc = fmaf(f, __high2float(hw[2]), __low2float(hw[2]));
    float wd = fmaf(f, __high2float(hw[3]), __low2float(hw[3]));

    float dot = e.s1.x * shx + e.s1.y * shy + e.s1.z * shz;
    acc0 += wa * e.s0 + wd * dot;
    float wcs0 = wc * e.s0;
    accx = fmaf(wb, e.s1.x, fmaf(wcs0, shx, accx));
    accy = fmaf(wb, e.s1.y, fmaf(wcs0, shy, accy));
    accz = fmaf(wb, e.s1.z, fmaf(wcs0, shz, accz));
}

__global__ __launch_bounds__(256) void node_kernel(
    const float* __restrict__ nf,
    const uint4* __restrict__ lutp,
    const int* __restrict__ row_ptr,
    const float4* __restrict__ em,
    const float* __restrict__ lw0,
    const float* __restrict__ lw1,
    const float* __restrict__ g0,
    const float* __restrict__ be0,
    const float* __restrict__ g1,
    float* __restrict__ out,
    int N)
{
    __shared__ float s_agg[4][NDIM];
    int tid = threadIdx.x;
    int wave = tid >> 6;
    int lane = tid & 63;
    int n = blockIdx.x * 4 + wave;
    bool active = (n < N);

    int start = active ? row_ptr[n] : 0;
    int end   = active ? row_ptr[n + 1] : 0;

    float acc0 = 0.0f, accx = 0.0f, accy = 0.0f, accz = 0.0f;

    for (int j0 = start; j0 < end; j0 += 64) {
        int nk = end - j0;
        if (nk > 64) nk = 64;
        int idx = j0 + lane;
        if (idx >= end) idx = end - 1;
        float4 mm = em[idx];
        unsigned m_packed = __float_as_uint(mm.w);

        int k = 0;
        for (; k + 4 <= nk; k += 4) {
            EV e0 = grab_edge(k + 0, m_packed, lane, lutp, nf);
            EV e1 = grab_edge(k + 1, m_packed, lane, lutp, nf);
            EV e2 = grab_edge(k + 2, m_packed, lane, lutp, nf);
            EV e3 = grab_edge(k + 3, m_packed, lane, lutp, nf);
            accum_edge(e0, k + 0, mm.x, mm.y, mm.z, acc0, accx, accy, accz);
            accum_edge(e1, k + 1, mm.x, mm.y, mm.z, acc0, accx, accy, accz);
            accum_edge(e2, k + 2, mm.x, mm.y, mm.z, acc0, accx, accy, accz);
            accum_edge(e3, k + 3, mm.x, mm.y, mm.z, acc0, accx, accy, accz);
        }
        for (; k < nk; ++k) {
            EV e = grab_edge(k, m_packed, lane, lutp, nf);
            accum_edge(e, k, mm.x, mm.y, mm.z, acc0, accx, accy, accz);
        }
    }

    const float INVS2 = 0.7071067811865476f;
    s_agg[wave][lane]              = acc0 * INVS2;
    s_agg[wave][64 + 3 * lane + 0] = accx * INVS2;
    s_agg[wave][64 + 3 * lane + 1] = accy * INVS2;
    s_agg[wave][64 + 3 * lane + 2] = accz * INVS2;
    __syncthreads();

    const float* ag = s_agg[wave];
    float a0 = 0.0f, t1x = 0.0f, t1y = 0.0f, t1z = 0.0f;
    #pragma unroll 8
    for (int m = 0; m < 64; ++m) {
        float w0v = lw0[m * 64 + lane];
        float w1v = lw1[m * 64 + lane];
        float gg0 = ag[m];
        a0 = fmaf(gg0, w0v, a0);
        float gx = ag[64 + 3 * m + 0];
        float gy = ag[64 + 3 * m + 1];
        float gz = ag[64 + 3 * m + 2];
        t1x = fmaf(gx, w1v, t1x);
        t1y = fmaf(gy, w1v, t1y);
        t1z = fmaf(gz, w1v, t1z);
    }
    const float sc = 0.125f;  // 1/sqrt(64)
    a0 *= sc; t1x *= sc; t1y *= sc; t1z *= sc;

    // layernorm over a0 across 64 lanes
    float mu = a0;
    #pragma unroll
    for (int o = 32; o > 0; o >>= 1) mu += __shfl_xor(mu, o);
    mu *= (1.0f / 64.0f);
    float d = a0 - mu;
    float var = d * d;
    #pragma unroll
    for (int o = 32; o > 0; o >>= 1) var += __shfl_xor(var, o);
    var *= (1.0f / 64.0f);
    float o0 = g0[lane] * d * rsqrtf(var + 1e-5f) + be0[lane];

    // RMS over vnorm2 across 64 lanes
    float vn = t1x * t1x + t1y * t1y + t1z * t1z;
    float ms = vn;
    #pragma unroll
    for (int o = 32; o > 0; o >>= 1) ms += __shfl_xor(ms, o);
    ms *= (1.0f / 64.0f);
    float rinv = rsqrtf(ms + 1e-5f);
    float gg = g1[lane];

    if (active) {
        size_t b = (size_t)n * NDIM;
        out[b + lane] = nf[b + lane] + o0;
        float3 rv = ((const float3*)(nf + b + 64))[lane];
        float3 ov;
        ov.x = rv.x + gg * t1x * rinv;
        ov.y = rv.y + gg * t1y * rinv;
        ov.z = rv.z + gg * t1z * rinv;
        ((float3*)(out + b + 64))[lane] = ov;
    }
}

// ---------------------------------------------------------------------------
extern "C" void kernel_launch(void* const* d_in, const int* in_sizes, int n_in,
                              void* d_out, int out_size, void* d_ws, size_t ws_size,
                              hipStream_t stream)
{
    const float* nf   = (const float*)d_in[0];
    const int*   eidx = (const int*)d_in[1];
    const float* evec = (const float*)d_in[2];
    const float* elen = (const float*)d_in[3];
    const float* w1   = (const float*)d_in[4];
    const float* b1   = (const float*)d_in[5];
    const float* w2   = (const float*)d_in[6];
    const float* b2   = (const float*)d_in[7];
    const float* w3   = (const float*)d_in[8];
    const float* b3   = (const float*)d_in[9];
    const float* lw0  = (const float*)d_in[10];
    const float* lw1  = (const float*)d_in[11];
    const float* g0   = (const float*)d_in[12];
    const float* be0  = (const float*)d_in[13];
    const float* g1   = (const float*)d_in[14];

    int N = in_sizes[0] / NDIM;
    int E = in_sizes[3];

    char* ws = (char*)d_ws;
    size_t off = 0;
    auto align256 = [&]() { off = (off + 255) & ~(size_t)255; };
    float* lutv = (float*)(ws + off);   off += (size_t)LUT_N * NDIM * 4;      align256();
    uint4* lutp = (uint4*)(ws + off);   off += (size_t)LUT_N * 64 * 16;       align256();
    int* counts = (int*)(ws + off);     off += (size_t)N * 4;                 align256();
    int* row_ptr = (int*)(ws + off);    off += (size_t)(N + 1) * 4;           align256();
    int* cursor = (int*)(ws + off);     off += (size_t)N * 4;                 align256();
    float4* em = (float4*)(ws + off);   off += (size_t)E * 16;

    const int* row = eidx;
    const int* col = eidx + E;

    hipMemsetAsync(counts, 0, (size_t)N * 4, stream);
    lut_kernel<<<LUT_N, 64, 0, stream>>>(w1, b1, w2, b2, w3, b3, lutv);
    pack_kernel<<<(LUT_N * 64 + 255) / 256, 256, 0, stream>>>(lutv, lutp, LUT_N);
    hist_kernel<<<(E + 511) / 512, 512, 0, stream>>>(col, E, counts);
    scan_kernel<<<1, 1024, 0, stream>>>(counts, row_ptr, cursor, N);
    scatter_kernel<<<(E + 511) / 512, 512, 0, stream>>>(row, col, evec, elen, E, cursor, em);
    node_kernel<<<(N + 3) / 4, 256, 0, stream>>>(nf, lutp, row_ptr, em,
                                                 lw0, lw1, g0, be0, g1,
                                                 (float*)d_out, N);
}

// Round 4
// 261.548 us; speedup vs baseline: 1.4336x; 1.2133x over previous
//
#include <hip/hip_runtime.h>
#include <hip/hip_fp16.h>

#define NDIM 256
#define LUT_N 2048
#define LUT_BLOCKS (LUT_N / 4)   // 4 waves/block, one LUT row-pair per wave

// ---------------------------------------------------------------------------
// Fused prep kernel:
//   blocks [0, LUT_BLOCKS)            : LUT build + fp16 (value,delta) pack
//   blocks [LUT_BLOCKS, +histBlocks)  : histogram of col with rank capture
// ---------------------------------------------------------------------------
__global__ __launch_bounds__(256) void prep_kernel(
    const float* __restrict__ w1, const float* __restrict__ b1,
    const float* __restrict__ w2, const float* __restrict__ b2,
    const float* __restrict__ w3, const float* __restrict__ b3,
    uint4* __restrict__ lutp,
    const int* __restrict__ col, int E,
    int* __restrict__ counts, int* __restrict__ rank)
{
    if (blockIdx.x >= LUT_BLOCKS) {
        // ---- histogram part ----
        int i = (blockIdx.x - LUT_BLOCKS) * 256 + threadIdx.x;
        if (i < E) rank[i] = atomicAdd(&counts[col[i]], 1);
        return;
    }

    // ---- LUT part: wave computes LUT rows p and p+1 (for delta) ----
    __shared__ float h1[4][2][64];
    __shared__ float h2[4][2][64];
    int tid = threadIdx.x;
    int wave = tid >> 6;
    int j = tid & 63;
    int p = blockIdx.x * 4 + wave;
    int pn = (p < LUT_N - 1) ? p + 1 : p;
    const float step = 4.5f / (float)(LUT_N - 1);
    float ra = 0.5f + step * (float)p;
    float rb = 0.5f + step * (float)pn;

    const float cnorm = 0.6324555320336759f;  // sqrt(2/5)
    float acca = b1[j], accb = acca;
    #pragma unroll
    for (int k = 0; k < 8; ++k) {
        float freq = (float)(k + 1) * (3.14159265358979323846f / 5.0f);
        float wv = w1[k * 64 + j];
        acca = fmaf(cnorm * sinf(freq * ra) / ra, wv, acca);
        accb = fmaf(cnorm * sinf(freq * rb) / rb, wv, accb);
    }
    h1[wave][0][j] = acca / (1.0f + expf(-acca));
    h1[wave][1][j] = accb / (1.0f + expf(-accb));
    __syncthreads();

    acca = b2[j]; accb = acca;
    #pragma unroll 8
    for (int m = 0; m < 64; ++m) {
        float wv = w2[m * 64 + j];
        acca = fmaf(h1[wave][0][m], wv, acca);
        accb = fmaf(h1[wave][1][m], wv, accb);
    }
    h2[wave][0][j] = acca / (1.0f + expf(-acca));
    h2[wave][1][j] = accb / (1.0f + expf(-accb));
    __syncthreads();

    float ua = ra * 0.2f, ub = rb * 0.2f;
    float ua5 = ua * ua * ua * ua * ua, ub5 = ub * ub * ub * ub * ub;
    float enva = (ua < 1.0f) ? (1.0f - 21.0f * ua5 + 35.0f * ua5 * ua - 15.0f * ua5 * ua * ua) : 0.0f;
    float envb = (ub < 1.0f) ? (1.0f - 21.0f * ub5 + 35.0f * ub5 * ub - 15.0f * ub5 * ub * ub) : 0.0f;

    uint4 o;
    unsigned* ow = &o.x;
    #pragma unroll
    for (int q = 0; q < 4; ++q) {
        float oa = b3[q * 64 + j], ob = oa;
        #pragma unroll 8
        for (int m = 0; m < 64; ++m) {
            float wv = w3[m * 256 + q * 64 + j];
            oa = fmaf(h2[wave][0][m], wv, oa);
            ob = fmaf(h2[wave][1][m], wv, ob);
        }
        oa *= enva; ob *= envb;
        __half2 hh = __floats2half2_rn(oa, ob - oa);
        ow[q] = *reinterpret_cast<unsigned*>(&hh);
    }
    lutp[p * 64 + j] = o;
}

// ---------------------------------------------------------------------------
// Single-block scan: counts -> row_ptr (exclusive).
// ---------------------------------------------------------------------------
__global__ __launch_bounds__(1024) void scan_kernel(
    const int* __restrict__ counts, int* __restrict__ row_ptr, int N)
{
    __shared__ int partial[1024];
    int t = threadIdx.x;
    int ch = (N + 1023) >> 10;
    int base = t * ch;
    int sum = 0;
    for (int i = 0; i < ch; ++i) {
        int idx = base + i;
        if (idx < N) sum += counts[idx];
    }
    partial[t] = sum;
    __syncthreads();
    for (int o = 1; o < 1024; o <<= 1) {
        int add = (t >= o) ? partial[t - o] : 0;
        __syncthreads();
        partial[t] += add;
        __syncthreads();
    }
    int run = partial[t] - sum;
    for (int i = 0; i < ch; ++i) {
        int idx = base + i;
        if (idx < N) {
            row_ptr[idx] = run;
            run += counts[idx];
        }
    }
    if (t == 1023) row_ptr[N] = partial[1023];
}

// ---------------------------------------------------------------------------
// Atomic-free scatter: p = row_ptr[col] + rank.
// em = {shx, shy, shz, bits(rsrc | i0<<16 | fq<<27)}; needs N <= 65536.
// ---------------------------------------------------------------------------
__global__ void scatter_kernel(const int* __restrict__ row, const int* __restrict__ col,
                               const float* __restrict__ evec, const float* __restrict__ elen,
                               int E, const int* __restrict__ row_ptr,
                               const int* __restrict__ rank, float4* __restrict__ em)
{
    int i = blockIdx.x * 256 + threadIdx.x;
    if (i < E) {
        int p = row_ptr[col[i]] + rank[i];
        float vx = evec[3 * i + 0], vy = evec[3 * i + 1], vz = evec[3 * i + 2];
        float inv = rsqrtf(vx * vx + vy * vy + vz * vz) * 1.7320508075688772f; // sqrt(3)/|v|
        float x = (elen[i] - 0.5f) * ((float)(LUT_N - 1) / 4.5f);
        x = fminf(fmaxf(x, 0.0f), (float)(LUT_N - 1) - 1.0e-3f);
        int i0 = (int)x;
        if (i0 > LUT_N - 2) i0 = LUT_N - 2;
        float fr = x - (float)i0;
        int fq = (int)(fr * 32.0f);
        fq = fq < 0 ? 0 : (fq > 31 ? 31 : fq);
        unsigned packed = (unsigned)row[i] | ((unsigned)i0 << 16) | ((unsigned)fq << 27);
        em[p] = make_float4(vx * inv, vy * inv, vz * inv, __uint_as_float(packed));
    }
}

// ---------------------------------------------------------------------------
// Heavy kernel: one wave per destination node, lane = channel. (unchanged)
// ---------------------------------------------------------------------------
struct EV {
    uint4 L;      // 4x half2 (value,delta) for wa,wb,wc,wd
    float s0;
    float3 s1;
    unsigned packed;
};

__device__ __forceinline__ EV grab_edge(int k, unsigned m_packed, int lane,
                                        const uint4* __restrict__ lutp,
                                        const float* __restrict__ nf)
{
    EV e;
    e.packed = (unsigned)__shfl((int)m_packed, k);
    int rsrc = (int)(e.packed & 0xFFFFu);
    int i0 = (int)((e.packed >> 16) & 0x7FFu);
    e.L = lutp[i0 * 64 + lane];
    const float* nr = nf + (size_t)rsrc * NDIM;
    e.s0 = nr[lane];
    e.s1 = ((const float3*)(nr + 64))[lane];
    return e;
}

__device__ __forceinline__ void accum_edge(const EV& e, int k,
                                           float m_shx, float m_shy, float m_shz,
                                           float& acc0, float& accx, float& accy, float& accz)
{
    float shx = __shfl(m_shx, k);
    float shy = __shfl(m_shy, k);
    float shz = __shfl(m_shz, k);
    float f = (float)((e.packed >> 27) & 31u) * (1.0f / 32.0f) + (1.0f / 64.0f);

    const __half2* hw = reinterpret_cast<const __half2*>(&e.L);
    float wa = fmaf(f, __high2float(hw[0]), __low2float(hw[0]));
    float wb = fmaf(f, __high2float(hw[1]), __low2float(hw[1]));
    float wc = fmaf(f, __high2float(hw[2]), __low2float(hw[2]));
    float wd = fmaf(f, __high2float(hw[3]), __low2float(hw[3]));

    float dot = e.s1.x * shx + e.s1.y * shy + e.s1.z * shz;
    acc0 += wa * e.s0 + wd * dot;
    float wcs0 = wc * e.s0;
    accx = fmaf(wb, e.s1.x, fmaf(wcs0, shx, accx));
    accy = fmaf(wb, e.s1.y, fmaf(wcs0, shy, accy));
    accz = fmaf(wb, e.s1.z, fmaf(wcs0, shz, accz));
}

__global__ __launch_bounds__(256) void node_kernel(
    const float* __restrict__ nf,
    const uint4* __restrict__ lutp,
    const int* __restrict__ row_ptr,
    const float4* __restrict__ em,
    const float* __restrict__ lw0,
    const float* __restrict__ lw1,
    const float* __restrict__ g0,
    const float* __restrict__ be0,
    const float* __restrict__ g1,
    float* __restrict__ out,
    int N)
{
    __shared__ float s_agg[4][NDIM];
    int tid = threadIdx.x;
    int wave = tid >> 6;
    int lane = tid & 63;
    int n = blockIdx.x * 4 + wave;
    bool active = (n < N);

    int start = active ? row_ptr[n] : 0;
    int end   = active ? row_ptr[n + 1] : 0;

    float acc0 = 0.0f, accx = 0.0f, accy = 0.0f, accz = 0.0f;

    for (int j0 = start; j0 < end; j0 += 64) {
        int nk = end - j0;
        if (nk > 64) nk = 64;
        int idx = j0 + lane;
        if (idx >= end) idx = end - 1;
        float4 mm = em[idx];
        unsigned m_packed = __float_as_uint(mm.w);

        int k = 0;
        for (; k + 4 <= nk; k += 4) {
            EV e0 = grab_edge(k + 0, m_packed, lane, lutp, nf);
            EV e1 = grab_edge(k + 1, m_packed, lane, lutp, nf);
            EV e2 = grab_edge(k + 2, m_packed, lane, lutp, nf);
            EV e3 = grab_edge(k + 3, m_packed, lane, lutp, nf);
            accum_edge(e0, k + 0, mm.x, mm.y, mm.z, acc0, accx, accy, accz);
            accum_edge(e1, k + 1, mm.x, mm.y, mm.z, acc0, accx, accy, accz);
            accum_edge(e2, k + 2, mm.x, mm.y, mm.z, acc0, accx, accy, accz);
            accum_edge(e3, k + 3, mm.x, mm.y, mm.z, acc0, accx, accy, accz);
        }
        for (; k < nk; ++k) {
            EV e = grab_edge(k, m_packed, lane, lutp, nf);
            accum_edge(e, k, mm.x, mm.y, mm.z, acc0, accx, accy, accz);
        }
    }

    const float INVS2 = 0.7071067811865476f;
    s_agg[wave][lane]              = acc0 * INVS2;
    s_agg[wave][64 + 3 * lane + 0] = accx * INVS2;
    s_agg[wave][64 + 3 * lane + 1] = accy * INVS2;
    s_agg[wave][64 + 3 * lane + 2] = accz * INVS2;
    __syncthreads();

    const float* ag = s_agg[wave];
    float a0 = 0.0f, t1x = 0.0f, t1y = 0.0f, t1z = 0.0f;
    #pragma unroll 8
    for (int m = 0; m < 64; ++m) {
        float w0v = lw0[m * 64 + lane];
        float w1v = lw1[m * 64 + lane];
        float gg0 = ag[m];
        a0 = fmaf(gg0, w0v, a0);
        float gx = ag[64 + 3 * m + 0];
        float gy = ag[64 + 3 * m + 1];
        float gz = ag[64 + 3 * m + 2];
        t1x = fmaf(gx, w1v, t1x);
        t1y = fmaf(gy, w1v, t1y);
        t1z = fmaf(gz, w1v, t1z);
    }
    const float sc = 0.125f;  // 1/sqrt(64)
    a0 *= sc; t1x *= sc; t1y *= sc; t1z *= sc;

    // layernorm over a0 across 64 lanes
    float mu = a0;
    #pragma unroll
    for (int o = 32; o > 0; o >>= 1) mu += __shfl_xor(mu, o);
    mu *= (1.0f / 64.0f);
    float d = a0 - mu;
    float var = d * d;
    #pragma unroll
    for (int o = 32; o > 0; o >>= 1) var += __shfl_xor(var, o);
    var *= (1.0f / 64.0f);
    float o0 = g0[lane] * d * rsqrtf(var + 1e-5f) + be0[lane];

    // RMS over vnorm2 across 64 lanes
    float vn = t1x * t1x + t1y * t1y + t1z * t1z;
    float ms = vn;
    #pragma unroll
    for (int o = 32; o > 0; o >>= 1) ms += __shfl_xor(ms, o);
    ms *= (1.0f / 64.0f);
    float rinv = rsqrtf(ms + 1e-5f);
    float gg = g1[lane];

    if (active) {
        size_t b = (size_t)n * NDIM;
        out[b + lane] = nf[b + lane] + o0;
        float3 rv = ((const float3*)(nf + b + 64))[lane];
        float3 ov;
        ov.x = rv.x + gg * t1x * rinv;
        ov.y = rv.y + gg * t1y * rinv;
        ov.z = rv.z + gg * t1z * rinv;
        ((float3*)(out + b + 64))[lane] = ov;
    }
}

// ---------------------------------------------------------------------------
extern "C" void kernel_launch(void* const* d_in, const int* in_sizes, int n_in,
                              void* d_out, int out_size, void* d_ws, size_t ws_size,
                              hipStream_t stream)
{
    const float* nf   = (const float*)d_in[0];
    const int*   eidx = (const int*)d_in[1];
    const float* evec = (const float*)d_in[2];
    const float* elen = (const float*)d_in[3];
    const float* w1   = (const float*)d_in[4];
    const float* b1   = (const float*)d_in[5];
    const float* w2   = (const float*)d_in[6];
    const float* b2   = (const float*)d_in[7];
    const float* w3   = (const float*)d_in[8];
    const float* b3   = (const float*)d_in[9];
    const float* lw0  = (const float*)d_in[10];
    const float* lw1  = (const float*)d_in[11];
    const float* g0   = (const float*)d_in[12];
    const float* be0  = (const float*)d_in[13];
    const float* g1   = (const float*)d_in[14];

    int N = in_sizes[0] / NDIM;
    int E = in_sizes[3];

    char* ws = (char*)d_ws;
    size_t off = 0;
    auto align256 = [&]() { off = (off + 255) & ~(size_t)255; };
    uint4* lutp = (uint4*)(ws + off);   off += (size_t)LUT_N * 64 * 16;   align256();
    int* counts = (int*)(ws + off);     off += (size_t)N * 4;             align256();
    int* row_ptr = (int*)(ws + off);    off += (size_t)(N + 1) * 4;       align256();
    int* rank = (int*)(ws + off);       off += (size_t)E * 4;             align256();
    float4* em = (float4*)(ws + off);   off += (size_t)E * 16;

    const int* row = eidx;
    const int* col = eidx + E;

    int histBlocks = (E + 255) / 256;

    hipMemsetAsync(counts, 0, (size_t)N * 4, stream);
    prep_kernel<<<LUT_BLOCKS + histBlocks, 256, 0, stream>>>(
        w1, b1, w2, b2, w3, b3, lutp, col, E, counts, rank);
    scan_kernel<<<1, 1024, 0, stream>>>(counts, row_ptr, N);
    scatter_kernel<<<(E + 255) / 256, 256, 0, stream>>>(row, col, evec, elen, E,
                                                        row_ptr, rank, em);
    node_kernel<<<(N + 3) / 4, 256, 0, stream>>>(nf, lutp, row_ptr, em,
                                                 lw0, lw1, g0, be0, g1,
                                                 (float*)d_out, N);
}

// Round 5
// 201.484 us; speedup vs baseline: 1.8610x; 1.2981x over previous
//
#include <hip/hip_runtime.h>
#include <hip/hip_fp16.h>

#define NDIM 256
#define LUT_N 2048
#define LUT_BLOCKS (LUT_N / 4)   // 4 waves/block, one LUT row-pair per wave
#define SCAN_BLK 1024
#define NODE_BLOCKS 2048
#define NODE_WAVES (NODE_BLOCKS * 4)

// ---------------------------------------------------------------------------
// Fused prep kernel:
//   blocks [0, LUT_BLOCKS)            : LUT build + fp16 (value,delta) pack
//   blocks [LUT_BLOCKS, +histBlocks)  : histogram of col with rank capture
// ---------------------------------------------------------------------------
__global__ __launch_bounds__(256) void prep_kernel(
    const float* __restrict__ w1, const float* __restrict__ b1,
    const float* __restrict__ w2, const float* __restrict__ b2,
    const float* __restrict__ w3, const float* __restrict__ b3,
    uint4* __restrict__ lutp,
    const int* __restrict__ col, int E,
    int* __restrict__ counts, int* __restrict__ rank)
{
    if (blockIdx.x >= LUT_BLOCKS) {
        int i = (blockIdx.x - LUT_BLOCKS) * 256 + threadIdx.x;
        if (i < E) rank[i] = atomicAdd(&counts[col[i]], 1);
        return;
    }

    __shared__ float h1[4][2][64];
    __shared__ float h2[4][2][64];
    int tid = threadIdx.x;
    int wave = tid >> 6;
    int j = tid & 63;
    int p = blockIdx.x * 4 + wave;
    int pn = (p < LUT_N - 1) ? p + 1 : p;
    const float step = 4.5f / (float)(LUT_N - 1);
    float ra = 0.5f + step * (float)p;
    float rb = 0.5f + step * (float)pn;

    const float cnorm = 0.6324555320336759f;  // sqrt(2/5)
    float acca = b1[j], accb = acca;
    #pragma unroll
    for (int k = 0; k < 8; ++k) {
        float freq = (float)(k + 1) * (3.14159265358979323846f / 5.0f);
        float wv = w1[k * 64 + j];
        acca = fmaf(cnorm * sinf(freq * ra) / ra, wv, acca);
        accb = fmaf(cnorm * sinf(freq * rb) / rb, wv, accb);
    }
    h1[wave][0][j] = acca / (1.0f + expf(-acca));
    h1[wave][1][j] = accb / (1.0f + expf(-accb));
    __syncthreads();

    acca = b2[j]; accb = acca;
    #pragma unroll 8
    for (int m = 0; m < 64; ++m) {
        float wv = w2[m * 64 + j];
        acca = fmaf(h1[wave][0][m], wv, acca);
        accb = fmaf(h1[wave][1][m], wv, accb);
    }
    h2[wave][0][j] = acca / (1.0f + expf(-acca));
    h2[wave][1][j] = accb / (1.0f + expf(-accb));
    __syncthreads();

    float ua = ra * 0.2f, ub = rb * 0.2f;
    float ua5 = ua * ua * ua * ua * ua, ub5 = ub * ub * ub * ub * ub;
    float enva = (ua < 1.0f) ? (1.0f - 21.0f * ua5 + 35.0f * ua5 * ua - 15.0f * ua5 * ua * ua) : 0.0f;
    float envb = (ub < 1.0f) ? (1.0f - 21.0f * ub5 + 35.0f * ub5 * ub - 15.0f * ub5 * ub * ub) : 0.0f;

    uint4 o;
    unsigned* ow = &o.x;
    #pragma unroll
    for (int q = 0; q < 4; ++q) {
        float oa = b3[q * 64 + j], ob = oa;
        #pragma unroll 8
        for (int m = 0; m < 64; ++m) {
            float wv = w3[m * 256 + q * 64 + j];
            oa = fmaf(h2[wave][0][m], wv, oa);
            ob = fmaf(h2[wave][1][m], wv, ob);
        }
        oa *= enva; ob *= envb;
        __half2 hh = __floats2half2_rn(oa, ob - oa);
        ow[q] = *reinterpret_cast<unsigned*>(&hh);
    }
    lutp[p * 64 + j] = o;
}

// ---------------------------------------------------------------------------
// Two-level coalesced scan.
// scan1: per-1024-chunk exclusive scan (coalesced), emits chunk totals.
// scan2: one wave scans the chunk totals into off[].
// row_ptr[n] == loc[n] + off[n >> 10].
// ---------------------------------------------------------------------------
__global__ __launch_bounds__(SCAN_BLK) void scan1_kernel(
    const int* __restrict__ counts, int* __restrict__ loc,
    int* __restrict__ btot, int N)
{
    __shared__ int sh[SCAN_BLK];
    int t = threadIdx.x;
    int idx = blockIdx.x * SCAN_BLK + t;
    int v = (idx < N) ? counts[idx] : 0;
    sh[t] = v;
    __syncthreads();
    int acc = v;
    for (int o = 1; o < SCAN_BLK; o <<= 1) {
        int add = (t >= o) ? sh[t - o] : 0;
        __syncthreads();
        acc += add;
        sh[t] = acc;
        __syncthreads();
    }
    if (idx <= N) loc[idx] = acc - v;   // exclusive within chunk
    if (t == SCAN_BLK - 1) btot[blockIdx.x] = acc;
}

__global__ __launch_bounds__(64) void scan2_kernel(
    const int* __restrict__ btot, int* __restrict__ off, int nb)
{
    int t = threadIdx.x;
    int v = (t < nb) ? btot[t] : 0;
    int acc = v;
    #pragma unroll
    for (int o = 1; o < 64; o <<= 1) {
        int up = __shfl_up(acc, o);
        if (t >= o) acc += up;
    }
    if (t <= nb) off[t] = acc - v;      // exclusive
}

// ---------------------------------------------------------------------------
// Atomic-free scatter: p = loc[col] + off[col>>10] + rank.
// em = {shx, shy, shz, bits(rsrc | i0<<16 | fq<<27)}; needs N <= 65536.
// ---------------------------------------------------------------------------
__global__ void scatter_kernel(const int* __restrict__ row, const int* __restrict__ col,
                               const float* __restrict__ evec, const float* __restrict__ elen,
                               int E, const int* __restrict__ loc, const int* __restrict__ off,
                               const int* __restrict__ rank, float4* __restrict__ em)
{
    int i = blockIdx.x * 256 + threadIdx.x;
    if (i < E) {
        int c = col[i];
        int p = loc[c] + off[c >> 10] + rank[i];
        float vx = evec[3 * i + 0], vy = evec[3 * i + 1], vz = evec[3 * i + 2];
        float inv = rsqrtf(vx * vx + vy * vy + vz * vz) * 1.7320508075688772f; // sqrt(3)/|v|
        float x = (elen[i] - 0.5f) * ((float)(LUT_N - 1) / 4.5f);
        x = fminf(fmaxf(x, 0.0f), (float)(LUT_N - 1) - 1.0e-3f);
        int i0 = (int)x;
        if (i0 > LUT_N - 2) i0 = LUT_N - 2;
        float fr = x - (float)i0;
        int fq = (int)(fr * 32.0f);
        fq = fq < 0 ? 0 : (fq > 31 ? 31 : fq);
        unsigned packed = (unsigned)row[i] | ((unsigned)i0 << 16) | ((unsigned)fq << 27);
        em[p] = make_float4(vx * inv, vy * inv, vz * inv, __uint_as_float(packed));
    }
}

// ---------------------------------------------------------------------------
// Heavy kernel: persistent waves, each wave strides over nodes. No barriers;
// s_agg is wave-private (DS ops are in-order within a wave).
// ---------------------------------------------------------------------------
struct EV {
    uint4 L;      // 4x half2 (value,delta) for wa,wb,wc,wd
    float s0;
    float3 s1;
    unsigned packed;
};

__device__ __forceinline__ EV grab_edge(int k, unsigned m_packed, int lane,
                                        const uint4* __restrict__ lutp,
                                        const float* __restrict__ nf)
{
    EV e;
    e.packed = (unsigned)__shfl((int)m_packed, k);
    int rsrc = (int)(e.packed & 0xFFFFu);
    int i0 = (int)((e.packed >> 16) & 0x7FFu);
    e.L = lutp[i0 * 64 + lane];
    const float* nr = nf + (size_t)rsrc * NDIM;
    e.s0 = nr[lane];
    e.s1 = ((const float3*)(nr + 64))[lane];
    return e;
}

__device__ __forceinline__ void accum_edge(const EV& e, int k,
                                           float m_shx, float m_shy, float m_shz,
                                           float& acc0, float& accx, float& accy, float& accz)
{
    float shx = __shfl(m_shx, k);
    float shy = __shfl(m_shy, k);
    float shz = __shfl(m_shz, k);
    float f = (float)((e.packed >> 27) & 31u) * (1.0f / 32.0f) + (1.0f / 64.0f);

    const __half2* hw = reinterpret_cast<const __half2*>(&e.L);
    float wa = fmaf(f, __high2float(hw[0]), __low2float(hw[0]));
    float wb = fmaf(f, __high2float(hw[1]), __low2float(hw[1]));
    float wc = fmaf(f, __high2float(hw[2]), __low2float(hw[2]));
    float wd = fmaf(f, __high2float(hw[3]), __low2float(hw[3]));

    float dot = e.s1.x * shx + e.s1.y * shy + e.s1.z * shz;
    acc0 += wa * e.s0 + wd * dot;
    float wcs0 = wc * e.s0;
    accx = fmaf(wb, e.s1.x, fmaf(wcs0, shx, accx));
    accy = fmaf(wb, e.s1.y, fmaf(wcs0, shy, accy));
    accz = fmaf(wb, e.s1.z, fmaf(wcs0, shz, accz));
}

__global__ __launch_bounds__(256) void node_kernel(
    const float* __restrict__ nf,
    const uint4* __restrict__ lutp,
    const int* __restrict__ loc,
    const int* __restrict__ off,
    const float4* __restrict__ em,
    const float* __restrict__ lw0,
    const float* __restrict__ lw1,
    const float* __restrict__ g0,
    const float* __restrict__ be0,
    const float* __restrict__ g1,
    float* __restrict__ out,
    int N)
{
    __shared__ float s_agg[4][NDIM];
    int tid = threadIdx.x;
    int wave = tid >> 6;
    int lane = tid & 63;
    int w = blockIdx.x * 4 + wave;
    float* ag = s_agg[wave];

    for (int n = w; n < N; n += NODE_WAVES) {
        int start = loc[n] + off[n >> 10];
        int end   = loc[n + 1] + off[(n + 1) >> 10];

        float acc0 = 0.0f, accx = 0.0f, accy = 0.0f, accz = 0.0f;

        for (int j0 = start; j0 < end; j0 += 64) {
            int nk = end - j0;
            if (nk > 64) nk = 64;
            int idx = j0 + lane;
            if (idx >= end) idx = end - 1;
            float4 mm = em[idx];
            unsigned m_packed = __float_as_uint(mm.w);

            int k = 0;
            for (; k + 4 <= nk; k += 4) {
                EV e0 = grab_edge(k + 0, m_packed, lane, lutp, nf);
                EV e1 = grab_edge(k + 1, m_packed, lane, lutp, nf);
                EV e2 = grab_edge(k + 2, m_packed, lane, lutp, nf);
                EV e3 = grab_edge(k + 3, m_packed, lane, lutp, nf);
                accum_edge(e0, k + 0, mm.x, mm.y, mm.z, acc0, accx, accy, accz);
                accum_edge(e1, k + 1, mm.x, mm.y, mm.z, acc0, accx, accy, accz);
                accum_edge(e2, k + 2, mm.x, mm.y, mm.z, acc0, accx, accy, accz);
                accum_edge(e3, k + 3, mm.x, mm.y, mm.z, acc0, accx, accy, accz);
            }
            for (; k < nk; ++k) {
                EV e = grab_edge(k, m_packed, lane, lutp, nf);
                accum_edge(e, k, mm.x, mm.y, mm.z, acc0, accx, accy, accz);
            }
        }

        const float INVS2 = 0.7071067811865476f;
        ag[lane]              = acc0 * INVS2;
        ag[64 + 3 * lane + 0] = accx * INVS2;
        ag[64 + 3 * lane + 1] = accy * INVS2;
        ag[64 + 3 * lane + 2] = accz * INVS2;
        // wave-private LDS; DS pipe is in-order within a wave -> no barrier

        float a0 = 0.0f, t1x = 0.0f, t1y = 0.0f, t1z = 0.0f;
        #pragma unroll 8
        for (int m = 0; m < 64; ++m) {
            float w0v = lw0[m * 64 + lane];
            float w1v = lw1[m * 64 + lane];
            float gg0 = ag[m];
            a0 = fmaf(gg0, w0v, a0);
            float gx = ag[64 + 3 * m + 0];
            float gy = ag[64 + 3 * m + 1];
            float gz = ag[64 + 3 * m + 2];
            t1x = fmaf(gx, w1v, t1x);
            t1y = fmaf(gy, w1v, t1y);
            t1z = fmaf(gz, w1v, t1z);
        }
        const float sc = 0.125f;  // 1/sqrt(64)
        a0 *= sc; t1x *= sc; t1y *= sc; t1z *= sc;

        // layernorm over a0 across 64 lanes
        float mu = a0;
        #pragma unroll
        for (int o = 32; o > 0; o >>= 1) mu += __shfl_xor(mu, o);
        mu *= (1.0f / 64.0f);
        float d = a0 - mu;
        float var = d * d;
        #pragma unroll
        for (int o = 32; o > 0; o >>= 1) var += __shfl_xor(var, o);
        var *= (1.0f / 64.0f);
        float o0 = g0[lane] * d * rsqrtf(var + 1e-5f) + be0[lane];

        // RMS over vnorm2 across 64 lanes
        float vn = t1x * t1x + t1y * t1y + t1z * t1z;
        float ms = vn;
        #pragma unroll
        for (int o = 32; o > 0; o >>= 1) ms += __shfl_xor(ms, o);
        ms *= (1.0f / 64.0f);
        float rinv = rsqrtf(ms + 1e-5f);
        float gg = g1[lane];

        size_t b = (size_t)n * NDIM;
        out[b + lane] = nf[b + lane] + o0;
        float3 rv = ((const float3*)(nf + b + 64))[lane];
        float3 ov;
        ov.x = rv.x + gg * t1x * rinv;
        ov.y = rv.y + gg * t1y * rinv;
        ov.z = rv.z + gg * t1z * rinv;
        ((float3*)(out + b + 64))[lane] = ov;
    }
}

// ---------------------------------------------------------------------------
extern "C" void kernel_launch(void* const* d_in, const int* in_sizes, int n_in,
                              void* d_out, int out_size, void* d_ws, size_t ws_size,
                              hipStream_t stream)
{
    const float* nf   = (const float*)d_in[0];
    const int*   eidx = (const int*)d_in[1];
    const float* evec = (const float*)d_in[2];
    const float* elen = (const float*)d_in[3];
    const float* w1   = (const float*)d_in[4];
    const float* b1   = (const float*)d_in[5];
    const float* w2   = (const float*)d_in[6];
    const float* b2   = (const float*)d_in[7];
    const float* w3   = (const float*)d_in[8];
    const float* b3   = (const float*)d_in[9];
    const float* lw0  = (const float*)d_in[10];
    const float* lw1  = (const float*)d_in[11];
    const float* g0   = (const float*)d_in[12];
    const float* be0  = (const float*)d_in[13];
    const float* g1   = (const float*)d_in[14];

    int N = in_sizes[0] / NDIM;
    int E = in_sizes[3];

    int nb = (N + SCAN_BLK) / SCAN_BLK;   // chunks covering idx range [0, N]

    char* ws = (char*)d_ws;
    size_t off_b = 0;
    auto align256 = [&]() { off_b = (off_b + 255) & ~(size_t)255; };
    uint4* lutp = (uint4*)(ws + off_b);   off_b += (size_t)LUT_N * 64 * 16;   align256();
    int* counts = (int*)(ws + off_b);     off_b += (size_t)N * 4;             align256();
    int* loc = (int*)(ws + off_b);        off_b += (size_t)(N + 1) * 4;       align256();
    int* btot = (int*)(ws + off_b);       off_b += (size_t)nb * 4;            align256();
    int* boff = (int*)(ws + off_b);       off_b += (size_t)(nb + 1) * 4;      align256();
    int* rank = (int*)(ws + off_b);       off_b += (size_t)E * 4;             align256();
    float4* em = (float4*)(ws + off_b);   off_b += (size_t)E * 16;

    const int* row = eidx;
    const int* col = eidx + E;

    int histBlocks = (E + 255) / 256;

    hipMemsetAsync(counts, 0, (size_t)N * 4, stream);
    prep_kernel<<<LUT_BLOCKS + histBlocks, 256, 0, stream>>>(
        w1, b1, w2, b2, w3, b3, lutp, col, E, counts, rank);
    scan1_kernel<<<nb, SCAN_BLK, 0, stream>>>(counts, loc, btot, N);
    scan2_kernel<<<1, 64, 0, stream>>>(btot, boff, nb);
    scatter_kernel<<<(E + 255) / 256, 256, 0, stream>>>(row, col, evec, elen, E,
                                                        loc, boff, rank, em);
    node_kernel<<<NODE_BLOCKS, 256, 0, stream>>>(nf, lutp, loc, boff, em,
                                                 lw0, lw1, g0, be0, g1,
                                                 (float*)d_out, N);
}